// Round 18
// baseline (539.856 us; speedup 1.0000x reference)
//
#include <hip/hip_runtime.h>
#include <hip/hip_bf16.h>
#include <stdint.h>

typedef unsigned short u16;
typedef __attribute__((ext_vector_type(8))) short s16x8;
typedef __attribute__((ext_vector_type(8))) unsigned short u16x8;
typedef __attribute__((ext_vector_type(4))) unsigned short u16x4;
typedef __attribute__((ext_vector_type(4))) float fx4;
typedef __bf16 bf16x8 __attribute__((ext_vector_type(8)));
typedef __fp16 h2 __attribute__((ext_vector_type(2)));

#define SEQ 2048
#define HID 4096
#define NHEAD 32
#define HDIM 128
#define P3H 12288
#define NKT 64  // K-tiles of 64 in the GEMM (4096/64)

__device__ __forceinline__ u16 f2bf(float f) {
  unsigned u = __builtin_bit_cast(unsigned, f);
  u += 0x7fffu + ((u >> 16) & 1u);          // RNE
  return (u16)(u >> 16);
}
__device__ __forceinline__ float bf2f(u16 h) {
  unsigned u = ((unsigned)h) << 16;
  return __builtin_bit_cast(float, u);
}
__device__ __forceinline__ void gload_lds16(const void* g, void* l) {
  __builtin_amdgcn_global_load_lds((const __attribute__((address_space(1))) void*)g,
                                   (__attribute__((address_space(3))) void*)l, 16, 0, 0);
}
__device__ __forceinline__ fx4 mfma16(s16x8 a, s16x8 b, fx4 c) {
  return __builtin_amdgcn_mfma_f32_16x16x32_bf16(
      __builtin_bit_cast(bf16x8, a), __builtin_bit_cast(bf16x8, b), c, 0, 0, 0);
}
__device__ __forceinline__ int pkmax_f16(int a, int b) {
  int r;
  asm("v_pk_max_f16 %0, %1, %2" : "=v"(r) : "v"(a), "v"(b));
  return r;
}

// ---------------- f32 -> bf16 convert (hidden + W_pack in one launch) ----------------
__global__ void k_cvt2(const float* __restrict__ s0, u16* __restrict__ d0, int n0,
                       const float* __restrict__ s1, u16* __restrict__ d1, int n1) {
  int i = blockIdx.x * blockDim.x + threadIdx.x;
  const float* src; u16* dst;
  if (i < n0) { src = s0; dst = d0; }
  else        { src = s1; dst = d1; i -= n0; if (i >= n1) return; }
  float4 v = reinterpret_cast<const float4*>(src)[i];
  u16x4 o;
  o[0] = f2bf(v.x); o[1] = f2bf(v.y); o[2] = f2bf(v.z); o[3] = f2bf(v.w);
  reinterpret_cast<u16x4*>(dst)[i] = o;
}

// ---------------- QKV GEMM + fused RoPE / V-transpose epilogue (R14, measured best) ----------------
__device__ __forceinline__ void stage_half(const u16* __restrict__ g, u16* l, int r0, int t) {
#pragma unroll
  for (int c = 0; c < 2; c++) {
    int row = r0 + c * 64 + (t >> 3);
    int blk = (t & 7) ^ ((t >> 3) & 7);
    gload_lds16(g + (size_t)row * HID + blk * 8, l + row * 64 + (t & 7) * 8);
  }
}

#define BAR_OPEN __builtin_amdgcn_s_barrier()
#define BAR_CLOSE do { __builtin_amdgcn_s_barrier(); __builtin_amdgcn_sched_barrier(0); } while (0)
#define LGKM0 do { asm volatile("s_waitcnt lgkmcnt(0)" ::: "memory"); \
                   __builtin_amdgcn_sched_barrier(0); } while (0)

#define LDA_QUAD(qm) do { \
  _Pragma("unroll") for (int mi = 0; mi < 4; mi++) \
  _Pragma("unroll") for (int ks = 0; ks < 2; ks++) { \
    int row = wrr + (qm) * 64 + mi * 16 + li; \
    aA[mi][ks] = *(const s16x8*)&Al[row * 64 + (((ks * 4 + lg) ^ (row & 7)) << 3)]; \
  } } while (0)

// B rows (= C cols) for wave: hh2*128 + qq2*32 + qn*64 + nn*16 + li
#define LDB_QUAD(qn) do { \
  _Pragma("unroll") for (int nn = 0; nn < 2; nn++) \
  _Pragma("unroll") for (int ks = 0; ks < 2; ks++) { \
    int row = hh2 * 128 + qq2 * 32 + (qn) * 64 + nn * 16 + li; \
    aB[qn][nn][ks] = *(const s16x8*)&Bl[row * 64 + (((ks * 4 + lg) ^ (row & 7)) << 3)]; \
  } } while (0)

#define MMA_QUAD(qm, qn) do { \
  _Pragma("unroll") for (int ks = 0; ks < 2; ks++) \
  _Pragma("unroll") for (int mi = 0; mi < 4; mi++) \
  _Pragma("unroll") for (int ni = 0; ni < 2; ni++) \
    acc[(qm) * 4 + mi][(qn) * 2 + ni] = \
        mfma16(aA[mi][ks], aB[qn][ni][ks], acc[(qm) * 4 + mi][(qn) * 2 + ni]); \
  } while (0)

// [col][row] bf16 tile with XOR swizzle (u16-index units)
#define LTIDX(c, r) (((c) << 8) + ((r) ^ (((c) & 31) << 3)))

__global__ void __launch_bounds__(512, 2) k_gemm_qkv(const u16* __restrict__ A,
                                                     const u16* __restrict__ W,
                                                     u16* __restrict__ qo,
                                                     u16* __restrict__ ko,
                                                     u16* __restrict__ vo,
                                                     const int* __restrict__ pos) {
  __shared__ u16 SM[2][2][256 * 64];   // [buf][A|B][256 rows x 64 k] = 128 KiB
  const int t = threadIdx.x;
  const int lane = t & 63;
  const int w = t >> 6;
  const int li = lane & 15, lg = lane >> 4;
  const int wr = w >> 2, wc = w & 3;
  const int wrr = wr * 128;
  const int hh2 = wc >> 1, qq2 = wc & 1;

  const int cpx = gridDim.x >> 3;
  const int swz = (blockIdx.x & 7) * cpx + (blockIdx.x >> 3);
  const int bm = swz / 48, bn = swz - bm * 48;
  const int m0 = bm * 256, n0 = bn * 256;

  const u16* Ag = A + (size_t)m0 * HID;
  const u16* Wg = W + (size_t)n0 * HID;

  fx4 acc[8][4];
#pragma unroll
  for (int i = 0; i < 8; i++)
#pragma unroll
    for (int j = 0; j < 4; j++) acc[i][j] = fx4{0.f, 0.f, 0.f, 0.f};
  s16x8 aA[4][2], aB[2][2][2];

  // ---- prologue: B(0), A(0), B(1) staged; wait for kt=0 resident
  stage_half(Wg, &SM[0][1][0], 0, t);
  stage_half(Wg, &SM[0][1][0], 128, t);
  stage_half(Ag, &SM[0][0][0], 0, t);
  stage_half(Ag, &SM[0][0][0], 128, t);
  stage_half(Wg + 64, &SM[1][1][0], 0, t);
  stage_half(Wg + 64, &SM[1][1][0], 128, t);
  asm volatile("s_waitcnt vmcnt(4)" ::: "memory");
  BAR_CLOSE;

  for (int kt = 0; kt < NKT; kt++) {
    const int cur = kt & 1;
    u16* Al = &SM[cur][0][0];
    u16* Bl = &SM[cur][1][0];
    u16* Anxt = &SM[cur ^ 1][0][0];
    const u16* Agn = Ag + (size_t)(kt + 1) * 64;
    const u16* Wgn = Wg + (size_t)(kt + 2) * 64;

    // ---- phase 0: A-quad0 + B-quad0 reads; stage A(kt+1) half0
    LDA_QUAD(0);
    LDB_QUAD(0);
    if (kt + 1 < NKT) stage_half(Agn, Anxt, 0, t);
    asm volatile("s_waitcnt lgkmcnt(8)" ::: "memory");
    BAR_OPEN;
    LGKM0;
    __builtin_amdgcn_s_setprio(1);
    MMA_QUAD(0, 0);
    __builtin_amdgcn_s_setprio(0);
    BAR_CLOSE;

    // ---- phase 1: B-quad1 reads; stage A(kt+1) half1
    LDB_QUAD(1);
    if (kt + 1 < NKT) stage_half(Agn, Anxt, 128, t);
    BAR_OPEN;
    LGKM0;
    __builtin_amdgcn_s_setprio(1);
    MMA_QUAD(0, 1);
    __builtin_amdgcn_s_setprio(0);
    BAR_CLOSE;

    // ---- phase 2: A-quad1 reads; stage B(kt+2) half0 (cur B dead after ph1)
    LDA_QUAD(1);
    if (kt + 2 < NKT) stage_half(Wgn, Bl, 0, t);
    BAR_OPEN;
    LGKM0;
    __builtin_amdgcn_s_setprio(1);
    MMA_QUAD(1, 1);
    __builtin_amdgcn_s_setprio(0);
    BAR_CLOSE;

    // ---- phase 3: stage B(kt+2) half1; counted vmcnt(4)
    if (kt + 2 < NKT) stage_half(Wgn, Bl, 128, t);
    BAR_OPEN;
    LGKM0;
    __builtin_amdgcn_s_setprio(1);
    MMA_QUAD(1, 0);
    __builtin_amdgcn_s_setprio(0);
    if (kt + 2 < NKT) {
      asm volatile("s_waitcnt vmcnt(4)" ::: "memory");   // leave B(kt+2) in flight
    } else {
      asm volatile("s_waitcnt vmcnt(0)" ::: "memory");   // tail: drain
    }
    BAR_CLOSE;
  }

  // ---- fused epilogue ----
  const int ttype = n0 >> 12;            // 0=Q, 1=K, 2=V
  const int h0 = (n0 & 4095) >> 7;       // first head in this 256-col tile
  const int bb = m0 >> 11;               // batch (2048 % 256 == 0)
  const int sB = m0 & 2047;              // seq start

  if (ttype < 2) {
    // Q/K: register-local RoPE (acc[mi][p] pairs with acc[mi][p+2]).
    u16* dst = (ttype == 0) ? qo : ko;
    const float LG2E4 = 0.2076205059304601f;       // log2(1e4)/64
    const float LG2_2PI = 2.6514961294723187f;     // log2(2*pi)
#pragma unroll
    for (int p = 0; p < 2; p++) {
      int d = qq2 * 32 + p * 16 + li;
      float invf2 = exp2f(__builtin_fmaf(-(float)d, LG2E4, -LG2_2PI));
#pragma unroll
      for (int mi = 0; mi < 8; mi++) {
        int r0 = wrr + mi * 16 + lg * 4;
        int4 p4 = *reinterpret_cast<const int4*>(&pos[m0 + r0]);
#pragma unroll
        for (int j = 0; j < 4; j++) {
          float pv = (float)((j == 0) ? p4.x : (j == 1) ? p4.y : (j == 2) ? p4.z : p4.w);
          float rev = pv * invf2;
          rev -= floorf(rev);
          float sn = __builtin_amdgcn_sinf(rev);
          float cs = __builtin_amdgcn_cosf(rev);
          float x1 = acc[mi][p][j], x2 = acc[mi][p + 2][j];
          size_t base = ((size_t)(bb * NHEAD + h0 + hh2) * SEQ + sB + r0 + j) * HDIM;
          dst[base + d]      = f2bf(x1 * cs - x2 * sn);
          dst[base + d + 64] = f2bf(x2 * cs + x1 * sn);
        }
      }
    }
  } else {
    // V: LDS-transpose epilogue. SM is dead after the final BAR_CLOSE.
    u16* LT = &SM[0][0][0];   // [256 cols][256 rows] bf16, swizzled = 128 KiB
#pragma unroll
    for (int mi = 0; mi < 8; mi++)
#pragma unroll
      for (int c2 = 0; c2 < 4; c2++) {
        u16x4 pk;
#pragma unroll
        for (int j = 0; j < 4; j++) pk[j] = f2bf(acc[mi][c2][j]);
        int c = hh2 * 128 + qq2 * 32 + (c2 >> 1) * 64 + (c2 & 1) * 16 + li;
        int r0 = wrr + mi * 16 + lg * 4;
        *reinterpret_cast<u16x4*>(&LT[LTIDX(c, r0)]) = pk;
      }
    __syncthreads();
    for (int it = 0; it < 16; ++it) {
      int cp = w * 16 + it;
      int c = cp * 2 + (lane >> 5);
      int ch = lane & 31;                 // 16B chunk = 8 rows
      u16x8 v = *reinterpret_cast<const u16x8*>(&LT[LTIDX(c, ch * 8)]);
      int hh = c >> 7, d = c & 127;
      size_t base = ((size_t)(bb * NHEAD + h0 + hh) * HDIM + d) * SEQ + sB;
      *reinterpret_cast<u16x8*>(&vo[base + ch * 8]) = v;
    }
  }
}

// ---------------- Flash attention (causal), swapped-QK^T, reduced-shfl softmax ----------------
// R14/R16 structure; softmax cross-lane traffic cut 8 -> 2 shfls per wave-tile:
// (1) row-max for BOTH q-groups reduced in ONE packed-f16 butterfly (v_pk_max_f16);
// (2) psum kept as per-lane partial, reduced once in the epilogue (rescales are
//     row-uniform multipliers, so deferral is exact).
__device__ __forceinline__ void stage_kv(const u16* __restrict__ kp, const u16* __restrict__ vp,
                                         u16* ksl, u16* vsl, int kv0, int t) {
#pragma unroll
  for (int c = 0; c < 4; c++) {           // K tile 64x128
    int row = c * 16 + (t >> 4);
    int cb = (t & 15) ^ (row & 7);
    gload_lds16(kp + (size_t)(kv0 + row) * HDIM + cb * 8, ksl + (size_t)(c * 256 + t) * 8);
  }
#pragma unroll
  for (int c = 0; c < 4; c++) {           // Vt tile 128x64
    int row = c * 32 + (t >> 3);
    int cb = (t & 7) ^ (row & 7);
    gload_lds16(vp + (size_t)row * SEQ + kv0 + cb * 8, vsl + (size_t)(c * 256 + t) * 8);
  }
}

__global__ void __launch_bounds__(256, 2) k_attn(const u16* __restrict__ q,
                                                 const u16* __restrict__ k,
                                                 const u16* __restrict__ vt,
                                                 float* __restrict__ out) {
  __shared__ u16 KVS[4][64 * 128];  // [0..1]=K bufs, [2..3]=V bufs (64 KB); epilogue scratch
  __shared__ u16 Ps[4][2][16 * 64]; // 16 KB (per-wave, per-group P tile)
  const int t = threadIdx.x;
  const int w = t >> 6, lane = t & 63;
  const int li = lane & 15, lg = lane >> 4;
  const int bh = blockIdx.x;                     // b*NHEAD + h, fastest dim
  const int qb = gridDim.y - 1 - blockIdx.y;     // heavy diagonal blocks first
  const int b = bh >> 5, h = bh & 31;
  const int qw = qb * 128 + w * 32;
  const u16* qp = q + (size_t)bh * SEQ * HDIM;
  const u16* kp = k + (size_t)bh * SEQ * HDIM;
  const u16* vp = vt + (size_t)bh * HDIM * SEQ;

  s16x8 bq[2][4];
#pragma unroll
  for (int g = 0; g < 2; g++)
#pragma unroll
    for (int kk = 0; kk < 4; kk++)
      bq[g][kk] = *reinterpret_cast<const s16x8*>(
          &qp[(size_t)(qw + g * 16 + li) * HDIM + kk * 32 + lg * 8]);

  fx4 Oacc[2][8];
#pragma unroll
  for (int g = 0; g < 2; g++)
#pragma unroll
    for (int nd = 0; nd < 8; nd++) Oacc[g][nd] = fx4{0.f, 0.f, 0.f, 0.f};
  float mrun[2] = {-1e30f, -1e30f}, lrun[2] = {0.f, 0.f};  // lrun: per-lane PARTIAL

  const float SC2 = 0.12752551286084110f;       // (1/sqrt(128)) * log2(e)
  const float THR = 8.0f / SC2;                 // defer-max threshold, raw domain
  const int nt = 2 * (qb + 1);
  const int psw = (li & 7) << 4;                // P swizzle byte mask

  stage_kv(kp, vp, KVS[0], KVS[2], 0, t);

  for (int tk = 0; tk < nt; tk++) {
    const int cur = tk & 1;
    if (tk + 1 < nt) {
      stage_kv(kp, vp, KVS[cur ^ 1], KVS[2 + (cur ^ 1)], (tk + 1) * 64, t);
      asm volatile("s_waitcnt vmcnt(8)" ::: "memory");   // drain tile tk only
    } else {
      asm volatile("s_waitcnt vmcnt(0)" ::: "memory");
    }
    __builtin_amdgcn_s_barrier();

    const u16* Kc = KVS[cur];
    const u16* Vc = KVS[2 + cur];
    const int kv0 = tk * 64;
    const bool diag = (tk >= 2 * qb);

    // ---- S^T = K Q^T for BOTH q-groups, K-frags read once
    fx4 sc[2][4];
#pragma unroll
    for (int g = 0; g < 2; g++)
#pragma unroll
      for (int n = 0; n < 4; n++) sc[g][n] = fx4{0.f, 0.f, 0.f, 0.f};
    __builtin_amdgcn_s_setprio(1);
#pragma unroll
    for (int n = 0; n < 4; n++) {
      int r = n * 16 + li;
#pragma unroll
      for (int kk = 0; kk < 4; kk++) {
        s16x8 ak = *reinterpret_cast<const s16x8*>(
            &Kc[r * 128 + (((kk * 4 + lg) ^ (r & 7)) << 3)]);
        sc[0][n] = mfma16(ak, bq[0][kk], sc[0][n]);
        sc[1][n] = mfma16(ak, bq[1][kk], sc[1][n]);
      }
    }
    __builtin_amdgcn_s_setprio(0);

    // ---- causal mask (raw domain)
    if (diag) {
#pragma unroll
      for (int g = 0; g < 2; g++) {
        const int qg = qw + g * 16 + li;
#pragma unroll
        for (int n = 0; n < 4; n++)
#pragma unroll
          for (int j = 0; j < 4; j++) {
            int kvg = kv0 + n * 16 + lg * 4 + j;
            if (kvg > qg) sc[g][n][j] = -1e30f;
          }
      }
    }

    // ---- row max, BOTH groups in one packed-f16 butterfly
    float vmax[2];
#pragma unroll
    for (int g = 0; g < 2; g++) {
      float mn0 = fmaxf(fmaxf(sc[g][0][0], sc[g][0][1]), fmaxf(sc[g][0][2], sc[g][0][3]));
      float mn1 = fmaxf(fmaxf(sc[g][1][0], sc[g][1][1]), fmaxf(sc[g][1][2], sc[g][1][3]));
      float mn2 = fmaxf(fmaxf(sc[g][2][0], sc[g][2][1]), fmaxf(sc[g][2][2], sc[g][2][3]));
      float mn3 = fmaxf(fmaxf(sc[g][3][0], sc[g][3][1]), fmaxf(sc[g][3][2], sc[g][3][3]));
      vmax[g] = fmaxf(fmaxf(mn0, mn1), fmaxf(mn2, mn3));
    }
    {
      h2 pm = __builtin_amdgcn_cvt_pkrtz(vmax[0], vmax[1]);
      int pi = __builtin_bit_cast(int, pm);
      pi = pkmax_f16(pi, __shfl_xor(pi, 16));
      pi = pkmax_f16(pi, __shfl_xor(pi, 32));
      pm = __builtin_bit_cast(h2, pi);
      vmax[0] = (float)pm[0];
      vmax[1] = (float)pm[1];
    }

#pragma unroll
    for (int g = 0; g < 2; g++) {
      if (__any(vmax[g] > mrun[g] + THR)) {
        float mnew = fmaxf(mrun[g], vmax[g]);
        float al = exp2f((mrun[g] - mnew) * SC2);
        mrun[g] = mnew;
        lrun[g] *= al;
        float alj[4];
#pragma unroll
        for (int j = 0; j < 4; j++) alj[j] = __shfl(al, lg * 4 + j);
#pragma unroll
        for (int nd = 0; nd < 8; nd++)
#pragma unroll
          for (int j = 0; j < 4; j++) Oacc[g][nd][j] *= alj[j];
      }
      const float mS = mrun[g] * SC2;
      float ps[4];
#pragma unroll
      for (int n = 0; n < 4; n++) {
        u16x4 pk;
        float pv0 = exp2f(__builtin_fmaf(sc[g][n][0], SC2, -mS));
        float pv1 = exp2f(__builtin_fmaf(sc[g][n][1], SC2, -mS));
        float pv2 = exp2f(__builtin_fmaf(sc[g][n][2], SC2, -mS));
        float pv3 = exp2f(__builtin_fmaf(sc[g][n][3], SC2, -mS));
        pk[0] = __builtin_bit_cast(u16, __float2bfloat16(pv0));
        pk[1] = __builtin_bit_cast(u16, __float2bfloat16(pv1));
        pk[2] = __builtin_bit_cast(u16, __float2bfloat16(pv2));
        pk[3] = __builtin_bit_cast(u16, __float2bfloat16(pv3));
        ps[n] = (pv0 + pv1) + (pv2 + pv3);
        *reinterpret_cast<u16x4*>(
            &Ps[w][g][li * 64 + (((n * 32 + lg * 8) ^ psw) >> 1)]) = pk;
      }
      lrun[g] += (ps[0] + ps[1]) + (ps[2] + ps[3]);   // per-lane partial (reduced at end)
    }

    // ---- O += P V for BOTH q-groups, V-frags read once
    s16x8 ap[2][2];
#pragma unroll
    for (int g = 0; g < 2; g++)
#pragma unroll
      for (int kvc = 0; kvc < 2; kvc++)
        ap[g][kvc] = *reinterpret_cast<const s16x8*>(
            &Ps[w][g][li * 64 + (((kvc * 64 + lg * 16) ^ psw) >> 1)]);
    __builtin_amdgcn_s_setprio(1);
#pragma unroll
    for (int nd = 0; nd < 8; nd++) {
      int dr = nd * 16 + li;
#pragma unroll
      for (int kvc = 0; kvc < 2; kvc++) {
        s16x8 bv = *reinterpret_cast<const s16x8*>(
            &Vc[dr * 64 + (((kvc * 4 + lg) ^ (dr & 7)) << 3)]);
        Oacc[0][nd] = mfma16(ap[0][kvc], bv, Oacc[0][nd]);
        Oacc[1][nd] = mfma16(ap[1][kvc], bv, Oacc[1][nd]);
      }
    }
    __builtin_amdgcn_s_setprio(0);

    __builtin_amdgcn_s_barrier();
    __builtin_amdgcn_sched_barrier(0);   // keep next iter's STAGE below this barrier
  }

  // ---- epilogue: reduce lrun partials (deferred), normalize via LDS scratch, float4 stores
  float lred[2];
#pragma unroll
  for (int g = 0; g < 2; g++) {
    float lr = lrun[g];
    lr += __shfl_xor(lr, 16);
    lr += __shfl_xor(lr, 32);
    lred[g] = lr;                        // all 4 lanes of a row now hold the full sum
  }
  float* scr = reinterpret_cast<float*>(&KVS[0][0]) + w * (16 * 132);  // 16 rows x stride 132
#pragma unroll
  for (int g = 0; g < 2; g++) {
#pragma unroll
    for (int j = 0; j < 4; j++) {
      float rl = 1.0f / __shfl(lred[g], lg * 4 + j);
      int row = lg * 4 + j;
#pragma unroll
      for (int nd = 0; nd < 8; nd++) scr[row * 132 + nd * 16 + li] = Oacc[g][nd][j] * rl;
    }
#pragma unroll
    for (int it = 0; it < 8; it++) {
      int idx = it * 64 + lane;
      int r = idx >> 5;            // 0..15
      int c4 = idx & 31;           // float4 index within the 128-d row
      float4 v = *reinterpret_cast<const float4*>(&scr[r * 132 + c4 * 4]);
      int s = qw + g * 16 + r;
      *reinterpret_cast<float4*>(
          &out[((size_t)(b * SEQ) + s) * HID + h * HDIM + c4 * 4]) = v;
    }
  }
}

extern "C" void kernel_launch(void* const* d_in, const int* in_sizes, int n_in,
                              void* d_out, int out_size, void* d_ws, size_t ws_size,
                              hipStream_t stream) {
  const float* hidden = (const float*)d_in[0];
  const float* wpack = (const float*)d_in[1];
  const int* pos = (const int*)d_in[3];
  float* out = (float*)d_out;

  char* ws = (char*)d_ws;
  // [0,32) hid_bf | [32,128) wp_bf | [128,160) q | [160,192) k | [192,224) vt
  u16* hid_bf = (u16*)ws;
  u16* wp_bf = (u16*)(ws + ((size_t)32 << 20));
  u16* qb = (u16*)(ws + ((size_t)128 << 20));
  u16* kb = (u16*)(ws + ((size_t)160 << 20));
  u16* vtb = (u16*)(ws + ((size_t)192 << 20));

  const int n4h = HID * HID / 4, n4w = P3H * HID / 4;
  k_cvt2<<<(n4h + n4w + 255) / 256, 256, 0, stream>>>(hidden, hid_bf, n4h, wpack, wp_bf, n4w);

  k_gemm_qkv<<<768, 512, 0, stream>>>(hid_bf, wp_bf, qb, kb, vtb, pos);

  dim3 ga(2 * NHEAD, SEQ / 128);   // bh fastest (XCD-local per head), qb descending
  k_attn<<<ga, 256, 0, stream>>>(qb, kb, vtb, out);
}

// Round 19
// 531.757 us; speedup vs baseline: 1.0152x; 1.0152x over previous
//
#include <hip/hip_runtime.h>
#include <hip/hip_bf16.h>
#include <stdint.h>

typedef unsigned short u16;
typedef __attribute__((ext_vector_type(8))) short s16x8;
typedef __attribute__((ext_vector_type(8))) unsigned short u16x8;
typedef __attribute__((ext_vector_type(4))) unsigned short u16x4;
typedef __attribute__((ext_vector_type(4))) float fx4;
typedef __bf16 bf16x8 __attribute__((ext_vector_type(8)));

#define SEQ 2048
#define HID 4096
#define NHEAD 32
#define HDIM 128
#define P3H 12288
#define NKT 64  // K-tiles of 64 in the GEMM (4096/64)

__device__ __forceinline__ u16 f2bf(float f) {
  unsigned u = __builtin_bit_cast(unsigned, f);
  u += 0x7fffu + ((u >> 16) & 1u);          // RNE
  return (u16)(u >> 16);
}
__device__ __forceinline__ float bf2f(u16 h) {
  unsigned u = ((unsigned)h) << 16;
  return __builtin_bit_cast(float, u);
}
__device__ __forceinline__ void gload_lds16(const void* g, void* l) {
  __builtin_amdgcn_global_load_lds((const __attribute__((address_space(1))) void*)g,
                                   (__attribute__((address_space(3))) void*)l, 16, 0, 0);
}
__device__ __forceinline__ fx4 mfma16(s16x8 a, s16x8 b, fx4 c) {
  return __builtin_amdgcn_mfma_f32_16x16x32_bf16(
      __builtin_bit_cast(bf16x8, a), __builtin_bit_cast(bf16x8, b), c, 0, 0, 0);
}

// ---------------- f32 -> bf16 convert (hidden + W_pack in one launch) ----------------
__global__ void k_cvt2(const float* __restrict__ s0, u16* __restrict__ d0, int n0,
                       const float* __restrict__ s1, u16* __restrict__ d1, int n1) {
  int i = blockIdx.x * blockDim.x + threadIdx.x;
  const float* src; u16* dst;
  if (i < n0) { src = s0; dst = d0; }
  else        { src = s1; dst = d1; i -= n0; if (i >= n1) return; }
  float4 v = reinterpret_cast<const float4*>(src)[i];
  u16x4 o;
  o[0] = f2bf(v.x); o[1] = f2bf(v.y); o[2] = f2bf(v.z); o[3] = f2bf(v.w);
  reinterpret_cast<u16x4*>(dst)[i] = o;
}

// ---------------- QKV GEMM + fused RoPE / V-transpose epilogue (measured best) ----------------
// Main loop: 256x256 8-phase, 16x16x32 MFMA (32x32x16 measured worse: R10 4-way
// row-multiplicity bank conflict). Wave->column remap: wave wc owns head hh=wc>>1,
// quarter qq=wc&1, ni-tiles at {0,16,64,80}+qq*32 within the head -> RoPE pair
// (d, d+64) sits in acc[mi][p] / acc[mi][p+2] of the SAME thread (register-local
// RoPE, no LDS, no serial loop). V epilogue: swizzled LDS transpose.
__device__ __forceinline__ void stage_half(const u16* __restrict__ g, u16* l, int r0, int t) {
#pragma unroll
  for (int c = 0; c < 2; c++) {
    int row = r0 + c * 64 + (t >> 3);
    int blk = (t & 7) ^ ((t >> 3) & 7);
    gload_lds16(g + (size_t)row * HID + blk * 8, l + row * 64 + (t & 7) * 8);
  }
}

#define BAR_OPEN __builtin_amdgcn_s_barrier()
#define BAR_CLOSE do { __builtin_amdgcn_s_barrier(); __builtin_amdgcn_sched_barrier(0); } while (0)
#define LGKM0 do { asm volatile("s_waitcnt lgkmcnt(0)" ::: "memory"); \
                   __builtin_amdgcn_sched_barrier(0); } while (0)

#define LDA_QUAD(qm) do { \
  _Pragma("unroll") for (int mi = 0; mi < 4; mi++) \
  _Pragma("unroll") for (int ks = 0; ks < 2; ks++) { \
    int row = wrr + (qm) * 64 + mi * 16 + li; \
    aA[mi][ks] = *(const s16x8*)&Al[row * 64 + (((ks * 4 + lg) ^ (row & 7)) << 3)]; \
  } } while (0)

// B rows (= C cols) for wave: hh2*128 + qq2*32 + qn*64 + nn*16 + li
#define LDB_QUAD(qn) do { \
  _Pragma("unroll") for (int nn = 0; nn < 2; nn++) \
  _Pragma("unroll") for (int ks = 0; ks < 2; ks++) { \
    int row = hh2 * 128 + qq2 * 32 + (qn) * 64 + nn * 16 + li; \
    aB[qn][nn][ks] = *(const s16x8*)&Bl[row * 64 + (((ks * 4 + lg) ^ (row & 7)) << 3)]; \
  } } while (0)

#define MMA_QUAD(qm, qn) do { \
  _Pragma("unroll") for (int ks = 0; ks < 2; ks++) \
  _Pragma("unroll") for (int mi = 0; mi < 4; mi++) \
  _Pragma("unroll") for (int ni = 0; ni < 2; ni++) \
    acc[(qm) * 4 + mi][(qn) * 2 + ni] = \
        mfma16(aA[mi][ks], aB[qn][ni][ks], acc[(qm) * 4 + mi][(qn) * 2 + ni]); \
  } while (0)

// [col][row] bf16 tile with XOR swizzle (u16-index units)
#define LTIDX(c, r) (((c) << 8) + ((r) ^ (((c) & 31) << 3)))

__global__ void __launch_bounds__(512, 2) k_gemm_qkv(const u16* __restrict__ A,
                                                     const u16* __restrict__ W,
                                                     u16* __restrict__ qo,
                                                     u16* __restrict__ ko,
                                                     u16* __restrict__ vo,
                                                     const int* __restrict__ pos) {
  __shared__ u16 SM[2][2][256 * 64];   // [buf][A|B][256 rows x 64 k] = 128 KiB
  const int t = threadIdx.x;
  const int lane = t & 63;
  const int w = t >> 6;
  const int li = lane & 15, lg = lane >> 4;
  const int wr = w >> 2, wc = w & 3;
  const int wrr = wr * 128;
  const int hh2 = wc >> 1, qq2 = wc & 1;

  const int cpx = gridDim.x >> 3;
  const int swz = (blockIdx.x & 7) * cpx + (blockIdx.x >> 3);
  const int bm = swz / 48, bn = swz - bm * 48;
  const int m0 = bm * 256, n0 = bn * 256;

  const u16* Ag = A + (size_t)m0 * HID;
  const u16* Wg = W + (size_t)n0 * HID;

  fx4 acc[8][4];
#pragma unroll
  for (int i = 0; i < 8; i++)
#pragma unroll
    for (int j = 0; j < 4; j++) acc[i][j] = fx4{0.f, 0.f, 0.f, 0.f};
  s16x8 aA[4][2], aB[2][2][2];

  // ---- prologue: B(0), A(0), B(1) staged; wait for kt=0 resident
  stage_half(Wg, &SM[0][1][0], 0, t);
  stage_half(Wg, &SM[0][1][0], 128, t);
  stage_half(Ag, &SM[0][0][0], 0, t);
  stage_half(Ag, &SM[0][0][0], 128, t);
  stage_half(Wg + 64, &SM[1][1][0], 0, t);
  stage_half(Wg + 64, &SM[1][1][0], 128, t);
  asm volatile("s_waitcnt vmcnt(4)" ::: "memory");
  BAR_CLOSE;

  for (int kt = 0; kt < NKT; kt++) {
    const int cur = kt & 1;
    u16* Al = &SM[cur][0][0];
    u16* Bl = &SM[cur][1][0];
    u16* Anxt = &SM[cur ^ 1][0][0];
    const u16* Agn = Ag + (size_t)(kt + 1) * 64;
    const u16* Wgn = Wg + (size_t)(kt + 2) * 64;

    // ---- phase 0: A-quad0 + B-quad0 reads; stage A(kt+1) half0
    LDA_QUAD(0);
    LDB_QUAD(0);
    if (kt + 1 < NKT) stage_half(Agn, Anxt, 0, t);
    asm volatile("s_waitcnt lgkmcnt(8)" ::: "memory");
    BAR_OPEN;
    LGKM0;
    __builtin_amdgcn_s_setprio(1);
    MMA_QUAD(0, 0);
    __builtin_amdgcn_s_setprio(0);
    BAR_CLOSE;

    // ---- phase 1: B-quad1 reads; stage A(kt+1) half1
    LDB_QUAD(1);
    if (kt + 1 < NKT) stage_half(Agn, Anxt, 128, t);
    BAR_OPEN;
    LGKM0;
    __builtin_amdgcn_s_setprio(1);
    MMA_QUAD(0, 1);
    __builtin_amdgcn_s_setprio(0);
    BAR_CLOSE;

    // ---- phase 2: A-quad1 reads; stage B(kt+2) half0 (cur B dead after ph1)
    LDA_QUAD(1);
    if (kt + 2 < NKT) stage_half(Wgn, Bl, 0, t);
    BAR_OPEN;
    LGKM0;
    __builtin_amdgcn_s_setprio(1);
    MMA_QUAD(1, 1);
    __builtin_amdgcn_s_setprio(0);
    BAR_CLOSE;

    // ---- phase 3: stage B(kt+2) half1; counted vmcnt(4)
    if (kt + 2 < NKT) stage_half(Wgn, Bl, 128, t);
    BAR_OPEN;
    LGKM0;
    __builtin_amdgcn_s_setprio(1);
    MMA_QUAD(1, 0);
    __builtin_amdgcn_s_setprio(0);
    if (kt + 2 < NKT) {
      asm volatile("s_waitcnt vmcnt(4)" ::: "memory");   // leave B(kt+2) in flight
    } else {
      asm volatile("s_waitcnt vmcnt(0)" ::: "memory");   // tail: drain
    }
    BAR_CLOSE;
  }

  // ---- fused epilogue ----
  const int ttype = n0 >> 12;            // 0=Q, 1=K, 2=V
  const int h0 = (n0 & 4095) >> 7;       // first head in this 256-col tile
  const int bb = m0 >> 11;               // batch (2048 % 256 == 0)
  const int sB = m0 & 2047;              // seq start

  if (ttype < 2) {
    // Q/K: register-local RoPE (acc[mi][p] pairs with acc[mi][p+2]).
    u16* dst = (ttype == 0) ? qo : ko;
    const float LG2E4 = 0.2076205059304601f;       // log2(1e4)/64
    const float LG2_2PI = 2.6514961294723187f;     // log2(2*pi)
#pragma unroll
    for (int p = 0; p < 2; p++) {
      int d = qq2 * 32 + p * 16 + li;
      float invf2 = exp2f(__builtin_fmaf(-(float)d, LG2E4, -LG2_2PI));
#pragma unroll
      for (int mi = 0; mi < 8; mi++) {
        int r0 = wrr + mi * 16 + lg * 4;
        int4 p4 = *reinterpret_cast<const int4*>(&pos[m0 + r0]);
#pragma unroll
        for (int j = 0; j < 4; j++) {
          float pv = (float)((j == 0) ? p4.x : (j == 1) ? p4.y : (j == 2) ? p4.z : p4.w);
          float rev = pv * invf2;
          rev -= floorf(rev);
          float sn = __builtin_amdgcn_sinf(rev);
          float cs = __builtin_amdgcn_cosf(rev);
          float x1 = acc[mi][p][j], x2 = acc[mi][p + 2][j];
          size_t base = ((size_t)(bb * NHEAD + h0 + hh2) * SEQ + sB + r0 + j) * HDIM;
          dst[base + d]      = f2bf(x1 * cs - x2 * sn);
          dst[base + d + 64] = f2bf(x2 * cs + x1 * sn);
        }
      }
    }
  } else {
    // V: LDS-transpose epilogue. SM is dead after the final BAR_CLOSE.
    u16* LT = &SM[0][0][0];   // [256 cols][256 rows] bf16, swizzled = 128 KiB
#pragma unroll
    for (int mi = 0; mi < 8; mi++)
#pragma unroll
      for (int c2 = 0; c2 < 4; c2++) {
        u16x4 pk;
#pragma unroll
        for (int j = 0; j < 4; j++) pk[j] = f2bf(acc[mi][c2][j]);
        int c = hh2 * 128 + qq2 * 32 + (c2 >> 1) * 64 + (c2 & 1) * 16 + li;
        int r0 = wrr + mi * 16 + lg * 4;
        *reinterpret_cast<u16x4*>(&LT[LTIDX(c, r0)]) = pk;
      }
    __syncthreads();
    for (int it = 0; it < 16; ++it) {
      int cp = w * 16 + it;
      int c = cp * 2 + (lane >> 5);
      int ch = lane & 31;                 // 16B chunk = 8 rows
      u16x8 v = *reinterpret_cast<const u16x8*>(&LT[LTIDX(c, ch * 8)]);
      int hh = c >> 7, d = c & 127;
      size_t base = ((size_t)(bb * NHEAD + h0 + hh) * HDIM + d) * SEQ + sB;
      *reinterpret_cast<u16x8*>(&vo[base + ch * 8]) = v;
    }
  }
}

// ---------------- Flash attention (causal), swapped-QK^T, XCD-local (b,h) grid ----------------
// Measured-best structure: QBLK=128, 4 waves, dbuf KVBLK=64, counted vmcnt, 2 blocks/CU;
// per-tile butterfly softmax (R18's reduced-shfl variant measured no better).
__device__ __forceinline__ void stage_kv(const u16* __restrict__ kp, const u16* __restrict__ vp,
                                         u16* ksl, u16* vsl, int kv0, int t) {
#pragma unroll
  for (int c = 0; c < 4; c++) {           // K tile 64x128
    int row = c * 16 + (t >> 4);
    int cb = (t & 15) ^ (row & 7);
    gload_lds16(kp + (size_t)(kv0 + row) * HDIM + cb * 8, ksl + (size_t)(c * 256 + t) * 8);
  }
#pragma unroll
  for (int c = 0; c < 4; c++) {           // Vt tile 128x64
    int row = c * 32 + (t >> 3);
    int cb = (t & 7) ^ (row & 7);
    gload_lds16(vp + (size_t)row * SEQ + kv0 + cb * 8, vsl + (size_t)(c * 256 + t) * 8);
  }
}

__global__ void __launch_bounds__(256, 2) k_attn(const u16* __restrict__ q,
                                                 const u16* __restrict__ k,
                                                 const u16* __restrict__ vt,
                                                 float* __restrict__ out) {
  __shared__ u16 Ks[2][64 * 128];   // 32 KB
  __shared__ u16 Vs[2][128 * 64];   // 32 KB
  __shared__ u16 Ps[4][2][16 * 64]; // 16 KB (per-wave, per-group P tile)
  const int t = threadIdx.x;
  const int w = t >> 6, lane = t & 63;
  const int li = lane & 15, lg = lane >> 4;
  const int bh = blockIdx.x;                     // b*NHEAD + h, fastest dim
  const int qb = gridDim.y - 1 - blockIdx.y;     // heavy diagonal blocks first
  const int b = bh >> 5, h = bh & 31;
  const int qw = qb * 128 + w * 32;
  const u16* qp = q + (size_t)bh * SEQ * HDIM;
  const u16* kp = k + (size_t)bh * SEQ * HDIM;
  const u16* vp = vt + (size_t)bh * HDIM * SEQ;

  s16x8 bq[2][4];
#pragma unroll
  for (int g = 0; g < 2; g++)
#pragma unroll
    for (int kk = 0; kk < 4; kk++)
      bq[g][kk] = *reinterpret_cast<const s16x8*>(
          &qp[(size_t)(qw + g * 16 + li) * HDIM + kk * 32 + lg * 8]);

  fx4 Oacc[2][8];
#pragma unroll
  for (int g = 0; g < 2; g++)
#pragma unroll
    for (int nd = 0; nd < 8; nd++) Oacc[g][nd] = fx4{0.f, 0.f, 0.f, 0.f};
  float mrun[2] = {-1e30f, -1e30f}, lrun[2] = {0.f, 0.f};

  const float SC2 = 0.12752551286084110f;       // (1/sqrt(128)) * log2(e)
  const float THR = 8.0f / SC2;                 // defer-max threshold, raw domain
  const int nt = 2 * (qb + 1);
  const int psw = (li & 7) << 4;                // P swizzle byte mask

  stage_kv(kp, vp, Ks[0], Vs[0], 0, t);

  for (int tk = 0; tk < nt; tk++) {
    const int cur = tk & 1;
    if (tk + 1 < nt) {
      stage_kv(kp, vp, Ks[cur ^ 1], Vs[cur ^ 1], (tk + 1) * 64, t);
      asm volatile("s_waitcnt vmcnt(8)" ::: "memory");   // drain tile tk only
    } else {
      asm volatile("s_waitcnt vmcnt(0)" ::: "memory");
    }
    __builtin_amdgcn_s_barrier();

    const u16* Kc = Ks[cur];
    const u16* Vc = Vs[cur];
    const int kv0 = tk * 64;
    const bool diag = (tk >= 2 * qb);

    // ---- S^T = K Q^T for BOTH q-groups, K-frags read once
    fx4 sc[2][4];
#pragma unroll
    for (int g = 0; g < 2; g++)
#pragma unroll
      for (int n = 0; n < 4; n++) sc[g][n] = fx4{0.f, 0.f, 0.f, 0.f};
    __builtin_amdgcn_s_setprio(1);
#pragma unroll
    for (int n = 0; n < 4; n++) {
      int r = n * 16 + li;
#pragma unroll
      for (int kk = 0; kk < 4; kk++) {
        s16x8 ak = *reinterpret_cast<const s16x8*>(
            &Kc[r * 128 + (((kk * 4 + lg) ^ (r & 7)) << 3)]);
        sc[0][n] = mfma16(ak, bq[0][kk], sc[0][n]);
        sc[1][n] = mfma16(ak, bq[1][kk], sc[1][n]);
      }
    }
    __builtin_amdgcn_s_setprio(0);

    // ---- causal mask (raw domain)
    if (diag) {
#pragma unroll
      for (int g = 0; g < 2; g++) {
        const int qg = qw + g * 16 + li;
#pragma unroll
        for (int n = 0; n < 4; n++)
#pragma unroll
          for (int j = 0; j < 4; j++) {
            int kvg = kv0 + n * 16 + lg * 4 + j;
            if (kvg > qg) sc[g][n][j] = -1e30f;
          }
      }
    }

    // ---- per-group softmax (raw-domain max; SC2 folded into exp2 via fma)
    s16x8 ap[2][2];
#pragma unroll
    for (int g = 0; g < 2; g++) {
      float mn[4];
#pragma unroll
      for (int n = 0; n < 4; n++)
        mn[n] = fmaxf(fmaxf(sc[g][n][0], sc[g][n][1]), fmaxf(sc[g][n][2], sc[g][n][3]));
      float vmax = fmaxf(fmaxf(mn[0], mn[1]), fmaxf(mn[2], mn[3]));
      vmax = fmaxf(vmax, __shfl_xor(vmax, 16));
      vmax = fmaxf(vmax, __shfl_xor(vmax, 32));
      if (__any(vmax > mrun[g] + THR)) {
        float mnew = fmaxf(mrun[g], vmax);
        float al = exp2f((mrun[g] - mnew) * SC2);
        mrun[g] = mnew;
        lrun[g] *= al;
        float alj[4];
#pragma unroll
        for (int j = 0; j < 4; j++) alj[j] = __shfl(al, lg * 4 + j);
#pragma unroll
        for (int nd = 0; nd < 8; nd++)
#pragma unroll
          for (int j = 0; j < 4; j++) Oacc[g][nd][j] *= alj[j];
      }
      const float mS = mrun[g] * SC2;
      float ps[4];
#pragma unroll
      for (int n = 0; n < 4; n++) {
        u16x4 pk;
        float pv0 = exp2f(__builtin_fmaf(sc[g][n][0], SC2, -mS));
        float pv1 = exp2f(__builtin_fmaf(sc[g][n][1], SC2, -mS));
        float pv2 = exp2f(__builtin_fmaf(sc[g][n][2], SC2, -mS));
        float pv3 = exp2f(__builtin_fmaf(sc[g][n][3], SC2, -mS));
        pk[0] = __builtin_bit_cast(u16, __float2bfloat16(pv0));
        pk[1] = __builtin_bit_cast(u16, __float2bfloat16(pv1));
        pk[2] = __builtin_bit_cast(u16, __float2bfloat16(pv2));
        pk[3] = __builtin_bit_cast(u16, __float2bfloat16(pv3));
        ps[n] = (pv0 + pv1) + (pv2 + pv3);
        *reinterpret_cast<u16x4*>(
            &Ps[w][g][li * 64 + (((n * 32 + lg * 8) ^ psw) >> 1)]) = pk;
      }
      float psum = (ps[0] + ps[1]) + (ps[2] + ps[3]);
      psum += __shfl_xor(psum, 16);
      psum += __shfl_xor(psum, 32);
      lrun[g] += psum;
#pragma unroll
      for (int kvc = 0; kvc < 2; kvc++)
        ap[g][kvc] = *reinterpret_cast<const s16x8*>(
            &Ps[w][g][li * 64 + (((kvc * 64 + lg * 16) ^ psw) >> 1)]);
    }

    // ---- O += P V for BOTH q-groups, V-frags read once
    __builtin_amdgcn_s_setprio(1);
#pragma unroll
    for (int nd = 0; nd < 8; nd++) {
      int dr = nd * 16 + li;
#pragma unroll
      for (int kvc = 0; kvc < 2; kvc++) {
        s16x8 bv = *reinterpret_cast<const s16x8*>(
            &Vc[dr * 64 + (((kvc * 4 + lg) ^ (dr & 7)) << 3)]);
        Oacc[0][nd] = mfma16(ap[0][kvc], bv, Oacc[0][nd]);
        Oacc[1][nd] = mfma16(ap[1][kvc], bv, Oacc[1][nd]);
      }
    }
    __builtin_amdgcn_s_setprio(0);

    __builtin_amdgcn_s_barrier();
    __builtin_amdgcn_sched_barrier(0);   // keep next iter's STAGE below this barrier
  }

  // ---- epilogue: fetch lrun for output rows (lg,j) via shfl, normalize, store
#pragma unroll
  for (int g = 0; g < 2; g++)
#pragma unroll
    for (int j = 0; j < 4; j++) {
      float rl = 1.0f / __shfl(lrun[g], lg * 4 + j);
      int s = qw + g * 16 + lg * 4 + j;
      float* op = out + ((size_t)(b * SEQ) + s) * HID + h * HDIM;
#pragma unroll
      for (int nd = 0; nd < 8; nd++) op[nd * 16 + li] = Oacc[g][nd][j] * rl;
    }
}

extern "C" void kernel_launch(void* const* d_in, const int* in_sizes, int n_in,
                              void* d_out, int out_size, void* d_ws, size_t ws_size,
                              hipStream_t stream) {
  const float* hidden = (const float*)d_in[0];
  const float* wpack = (const float*)d_in[1];
  const int* pos = (const int*)d_in[3];
  float* out = (float*)d_out;

  char* ws = (char*)d_ws;
  // [0,32) hid_bf | [32,128) wp_bf | [128,160) q | [160,192) k | [192,224) vt
  u16* hid_bf = (u16*)ws;
  u16* wp_bf = (u16*)(ws + ((size_t)32 << 20));
  u16* qb = (u16*)(ws + ((size_t)128 << 20));
  u16* kb = (u16*)(ws + ((size_t)160 << 20));
  u16* vtb = (u16*)(ws + ((size_t)192 << 20));

  const int n4h = HID * HID / 4, n4w = P3H * HID / 4;
  k_cvt2<<<(n4h + n4w + 255) / 256, 256, 0, stream>>>(hidden, hid_bf, n4h, wpack, wp_bf, n4w);

  k_gemm_qkv<<<768, 512, 0, stream>>>(hid_bf, wp_bf, qb, kb, vtb, pos);

  dim3 ga(2 * NHEAD, SEQ / 128);   // bh fastest (XCD-local per head), qb descending
  k_attn<<<ga, 256, 0, stream>>>(qb, kb, vtb, out);
}